// Round 1
// baseline (336.915 us; speedup 1.0000x reference)
//
#include <hip/hip_runtime.h>
#include <hip/hip_bf16.h>
#include <stdint.h>

#define DEVI __device__ __forceinline__

using u16 = unsigned short;
typedef __attribute__((ext_vector_type(8))) _Float16 halfx8;
typedef __attribute__((ext_vector_type(4))) float f32x4;

// Problem dims (fixed by the reference)
constexpr int BB = 4, TT = 2048, CC = 1024, KD = 1024, VD = 1024;
constexpr int OUTW = CC + VD;              // 2048
constexpr float INV_SQRT_K = 0.03125f;     // 1/sqrt(1024)

DEVI u16 f2h(float f) {
  _Float16 h = (_Float16)f;
  return __builtin_bit_cast(u16, h);
}

// ---- cast x to f16 (for MFMA) and copy x into out[:, :C] (fp32) ----
__global__ void cast_x_copy(const float* __restrict__ x, u16* __restrict__ xh,
                            float* __restrict__ out) {
  size_t i = (size_t)blockIdx.x * blockDim.x + threadIdx.x;  // over B*T*C/4
  float4 v = reinterpret_cast<const float4*>(x)[i];
  ushort4 u;
  u.x = f2h(v.x); u.y = f2h(v.y); u.z = f2h(v.z); u.w = f2h(v.w);
  reinterpret_cast<ushort4*>(xh)[i] = u;
  size_t e = i * 4;
  size_t bt = e / CC;
  int c = (int)(e % CC);
  *reinterpret_cast<float4*>(&out[bt * OUTW + c]) = v;
}

// ---- W [C,N] f32 -> Wt [N,C] f16 (so projections become A@B^T form) ----
__global__ void transpose_cast_w(const float* __restrict__ W, u16* __restrict__ Wt) {
  __shared__ float tile[32][33];
  int n0 = blockIdx.x * 32, c0 = blockIdx.y * 32;
  int tx = threadIdx.x, ty = threadIdx.y;  // 32 x 8
  for (int i = ty; i < 32; i += 8)
    tile[i][tx] = W[(size_t)(c0 + i) * KD + n0 + tx];
  __syncthreads();
  for (int i = ty; i < 32; i += 8)
    Wt[(size_t)(n0 + i) * CC + c0 + tx] = f2h(tile[tx][i]);
}

// ---- V [B,T,VD] f16 -> Vt [B,VD,T] f16 (so PV becomes A@B^T form) ----
__global__ void transpose_v(const u16* __restrict__ Vn, u16* __restrict__ Vt) {
  __shared__ u16 tile[32][33];
  int b = blockIdx.z;
  int n0 = blockIdx.x * 32, s0 = blockIdx.y * 32;
  const u16* src = Vn + (size_t)b * TT * VD;
  u16* dst = Vt + (size_t)b * VD * TT;
  int tx = threadIdx.x, ty = threadIdx.y;
  for (int i = ty; i < 32; i += 8)
    tile[i][tx] = src[(size_t)(s0 + i) * VD + n0 + tx];
  __syncthreads();
  for (int i = ty; i < 32; i += 8)
    dst[(size_t)(n0 + i) * TT + s0 + tx] = tile[tx][i];
}

// ---- generic f16 MFMA GEMM: Out = alpha * (A @ Bm^T) (+ bias) ----
// A: [M,Kd] row-major (lda), Bm: [N,Kd] row-major (ldb).
// CSKIP: skip tiles fully above the causal diagonal (QK^T — those S entries
//        are never read by the column-softmax).
// KLIM : truncate K at r0+BM (PV — P[t,s]==0 for s>t, exact).
template <typename OutT, bool CSKIP, bool KLIM, bool BIAS>
__global__ __launch_bounds__(256, 2) void gemm_bt(
    const u16* __restrict__ A, const u16* __restrict__ Bm, OutT* __restrict__ Out,
    const float* __restrict__ bias, int Kd, int lda, int ldb, int ldo,
    long long strA, long long strB, long long strO, float alpha) {
  constexpr int BM = 128, BN = 128, BK = 32, ROWP = 40;  // +8 pad: <=2-way LDS conflicts
  __shared__ u16 sA[BM * ROWP];
  __shared__ u16 sB[BN * ROWP];
  const int r0 = blockIdx.x * BM, c0 = blockIdx.y * BN;
  if (CSKIP && c0 > r0 + BM - 1) return;  // tile entirely masked; never read downstream
  A   += (size_t)blockIdx.z * strA;
  Bm  += (size_t)blockIdx.z * strB;
  Out += (size_t)blockIdx.z * strO;

  const int tid = threadIdx.x;
  const int lane = tid & 63;
  const int w = tid >> 6;
  // staging: thread covers row = tid>>1 (0..127), cols (tid&1)*16 + {0..7, 8..15}
  const int srow = tid >> 1, scol = (tid & 1) * 16;
  const u16* gA = A + (size_t)(r0 + srow) * lda + scol;
  const u16* gB = Bm + (size_t)(c0 + srow) * ldb + scol;
  u16* stA = &sA[srow * ROWP + scol];
  u16* stB = &sB[srow * ROWP + scol];

  const int wr = (w >> 1) * 64, wc = (w & 1) * 64;  // wave's 64x64 quadrant
  const int l15 = lane & 15, l4 = lane >> 4;

  f32x4 acc[4][4] = {};

  int kmax = Kd;
  if (KLIM) { int km = r0 + BM; kmax = km < Kd ? km : Kd; }

  for (int k0 = 0; k0 < kmax; k0 += BK) {
    // issue global loads early (overlap previous iteration's MFMA)
    halfx8 ra0 = *reinterpret_cast<const halfx8*>(gA + k0);
    halfx8 ra1 = *reinterpret_cast<const halfx8*>(gA + k0 + 8);
    halfx8 rb0 = *reinterpret_cast<const halfx8*>(gB + k0);
    halfx8 rb1 = *reinterpret_cast<const halfx8*>(gB + k0 + 8);
    __syncthreads();  // previous iteration's LDS reads done
    *reinterpret_cast<halfx8*>(stA)     = ra0;
    *reinterpret_cast<halfx8*>(stA + 8) = ra1;
    *reinterpret_cast<halfx8*>(stB)     = rb0;
    *reinterpret_cast<halfx8*>(stB + 8) = rb1;
    __syncthreads();
    halfx8 af[4], bfr[4];
#pragma unroll
    for (int m = 0; m < 4; ++m)
      af[m] = *reinterpret_cast<const halfx8*>(&sA[(wr + m * 16 + l15) * ROWP + l4 * 8]);
#pragma unroll
    for (int n = 0; n < 4; ++n)
      bfr[n] = *reinterpret_cast<const halfx8*>(&sB[(wc + n * 16 + l15) * ROWP + l4 * 8]);
#pragma unroll
    for (int m = 0; m < 4; ++m)
#pragma unroll
      for (int n = 0; n < 4; ++n)
        acc[m][n] = __builtin_amdgcn_mfma_f32_16x16x32_f16(af[m], bfr[n], acc[m][n], 0, 0, 0);
  }

  // epilogue: C/D layout col = lane&15, row = (lane>>4)*4 + reg  [m89/m91 verified]
#pragma unroll
  for (int m = 0; m < 4; ++m) {
    const int growb = r0 + wr + m * 16 + l4 * 4;
#pragma unroll
    for (int n = 0; n < 4; ++n) {
      const int gcol = c0 + wc + n * 16 + l15;
      float bvv = 0.f;
      if (BIAS) bvv = bias[gcol];
#pragma unroll
      for (int r = 0; r < 4; ++r) {
        float val = acc[m][n][r] * alpha + bvv;
        size_t off = (size_t)(growb + r) * ldo + gcol;
        if constexpr (sizeof(OutT) == 2) {
          reinterpret_cast<u16*>(Out)[off] = f2h(val);
        } else {
          reinterpret_cast<float*>(Out)[off] = val;
        }
      }
    }
  }
}

// ---- column softmax over t (axis=1), masked to t >= s ----
// Pass 1: per-(t-chunk) online partial (max, sum) per column s.
constexpr int TCH = 256;
__global__ void stats_partial(const float* __restrict__ S, float* __restrict__ Mp,
                              float* __restrict__ Dp) {
  int b = blockIdx.z;
  int s = blockIdx.x * 256 + threadIdx.x;
  int s0 = blockIdx.x * 256;
  int t0 = blockIdx.y * TCH;
  const float* Sb = S + (size_t)b * TT * TT;
  float m = -1e30f, d = 0.f;
  if (t0 + TCH - 1 >= s0) {
    for (int t = t0; t < t0 + TCH; ++t) {
      if (t >= s) {
        float v = Sb[(size_t)t * TT + s];
        float mn = fmaxf(m, v);
        d = d * __expf(m - mn) + __expf(v - mn);
        m = mn;
      }
    }
  }
  int idx = (blockIdx.y * BB + b) * TT + s;
  Mp[idx] = m;
  Dp[idx] = d;
}

// Pass 2: combine partials -> column max + 1/denominator
__global__ void stats_combine(const float* __restrict__ Mp, const float* __restrict__ Dp,
                              float* __restrict__ Mc, float* __restrict__ Di) {
  int b = blockIdx.y;
  int s = blockIdx.x * 256 + threadIdx.x;
  float m = -1e30f;
  for (int c = 0; c < TT / TCH; ++c) m = fmaxf(m, Mp[(c * BB + b) * TT + s]);
  float d = 0.f;
  for (int c = 0; c < TT / TCH; ++c)
    d += Dp[(c * BB + b) * TT + s] * __expf(Mp[(c * BB + b) * TT + s] - m);
  Mc[b * TT + s] = m;
  Di[b * TT + s] = 1.f / d;  // column always contains the diagonal -> d >= 1
}

// Pass 3: P[t,s] = exp(S[t,s]-M[s])/D[s] for t>=s else 0, stored f16
constexpr int ATCH = 64;
__global__ void softmax_apply(const float* __restrict__ S, const float* __restrict__ Mc,
                              const float* __restrict__ Di, u16* __restrict__ P) {
  int b = blockIdx.z;
  int s = blockIdx.x * 256 + threadIdx.x;
  int s0 = blockIdx.x * 256;
  int t0 = blockIdx.y * ATCH;
  if (s0 > ((t0 + ATCH - 1) | 127)) return;  // outside any PV-read tile band
  const float* Sb = S + (size_t)b * TT * TT;
  u16* Pb = P + (size_t)b * TT * TT;
  float m = Mc[b * TT + s], di = Di[b * TT + s];
  for (int t = t0; t < t0 + ATCH; ++t) {
    float p = 0.f;
    if (t >= s) p = __expf(Sb[(size_t)t * TT + s] - m) * di;
    Pb[(size_t)t * TT + s] = f2h(p);
  }
}

extern "C" void kernel_launch(void* const* d_in, const int* in_sizes, int n_in,
                              void* d_out, int out_size, void* d_ws, size_t ws_size,
                              hipStream_t stream) {
  const float* x  = (const float*)d_in[0];
  const float* Wq = (const float*)d_in[1];
  const float* bq = (const float*)d_in[2];
  const float* Wk = (const float*)d_in[3];
  const float* bk = (const float*)d_in[4];
  const float* Wv = (const float*)d_in[5];
  const float* bv = (const float*)d_in[6];
  float* out = (float*)d_out;
  char* ws = (char*)d_ws;
  constexpr size_t MB = 1024ull * 1024ull;

  // Workspace layout (total ~135 MB), with safe sequential-reuse aliases:
  u16* xh   = (u16*)(ws);              // 16 MB  [B*T,C] f16
  u16* Qh   = (u16*)(ws + 16 * MB);    // 16 MB
  u16* Kh   = (u16*)(ws + 32 * MB);    // 16 MB
  u16* Vh   = (u16*)(ws + 48 * MB);    // 16 MB
  u16* Wqt  = (u16*)(ws + 64 * MB);    // 2 MB   [K,C]
  u16* Wkt  = (u16*)(ws + 66 * MB);    // 2 MB
  u16* Wvt  = (u16*)(ws + 68 * MB);    // 2 MB
  float* Mp = (float*)(ws + 70 * MB);            // 256 KB partial max
  float* Dp = (float*)(ws + 70 * MB + 256 * 1024);  // 256 KB partial sum
  float* Mc = (float*)(ws + 70 * MB + 512 * 1024);  // 32 KB col max
  float* Di = (float*)(ws + 70 * MB + 544 * 1024);  // 32 KB 1/denom
  float* S  = (float*)(ws + 71 * MB);  // 64 MB  [B,T,T] fp32 logits
  u16* Vt = xh;  // alias: xh dead after V projection; Vt [B,VD,T]
  u16* P  = Qh;  // alias: Qh+Kh (32MB) dead after S GEMM; P [B,T,T] f16

  cast_x_copy<<<dim3((BB * TT * CC / 4) / 256), dim3(256), 0, stream>>>(x, xh, out);
  dim3 tb(32, 8);
  transpose_cast_w<<<dim3(KD / 32, CC / 32), tb, 0, stream>>>(Wq, Wqt);
  transpose_cast_w<<<dim3(KD / 32, CC / 32), tb, 0, stream>>>(Wk, Wkt);
  transpose_cast_w<<<dim3(VD / 32, CC / 32), tb, 0, stream>>>(Wv, Wvt);

  // projections: Q/K/V = xh @ Wt^T + b   -> f16 [8192,1024]
  gemm_bt<u16, false, false, true><<<dim3(64, 8, 1), 256, 0, stream>>>(
      xh, Wqt, Qh, bq, CC, CC, CC, KD, 0, 0, 0, 1.f);
  gemm_bt<u16, false, false, true><<<dim3(64, 8, 1), 256, 0, stream>>>(
      xh, Wkt, Kh, bk, CC, CC, CC, KD, 0, 0, 0, 1.f);
  gemm_bt<u16, false, false, true><<<dim3(64, 8, 1), 256, 0, stream>>>(
      xh, Wvt, Vh, bv, CC, CC, CC, VD, 0, 0, 0, 1.f);

  transpose_v<<<dim3(VD / 32, TT / 32, BB), tb, 0, stream>>>(Vh, Vt);

  // S = (Q @ K^T) / sqrt(K), causal tiles skipped
  gemm_bt<float, true, false, false><<<dim3(TT / 128, TT / 128, BB), 256, 0, stream>>>(
      Qh, Kh, S, nullptr, KD, KD, KD, TT,
      (long long)TT * KD, (long long)TT * KD, (long long)TT * TT, INV_SQRT_K);

  // column softmax over t (axis=1)
  stats_partial<<<dim3(TT / 256, TT / TCH, BB), 256, 0, stream>>>(S, Mp, Dp);
  stats_combine<<<dim3(TT / 256, BB), 256, 0, stream>>>(Mp, Dp, Mc, Di);
  softmax_apply<<<dim3(TT / 256, TT / ATCH, BB), 256, 0, stream>>>(S, Mc, Di, P);

  // read = P @ V  (= P @ Vt^T), K truncated at r0+128 (exact: P==0 above diag)
  gemm_bt<float, false, true, false><<<dim3(TT / 128, VD / 128, BB), 256, 0, stream>>>(
      P, Vt, out + CC, nullptr, TT, TT, TT, OUTW,
      (long long)TT * TT, (long long)VD * TT, (long long)TT * OUTW, 1.f);
}

// Round 2
// 277.898 us; speedup vs baseline: 1.2124x; 1.2124x over previous
//
#include <hip/hip_runtime.h>
#include <hip/hip_bf16.h>
#include <stdint.h>

#define DEVI __device__ __forceinline__

using u16 = unsigned short;
typedef __attribute__((ext_vector_type(8))) _Float16 halfx8;
typedef __attribute__((ext_vector_type(4))) float f32x4;

// Problem dims (fixed by the reference)
constexpr int BB = 4, TT = 2048, CC = 1024, KD = 1024, VD = 1024;
constexpr int OUTW = CC + VD;              // 2048
constexpr float INV_SQRT_K = 0.03125f;     // 1/sqrt(1024)

DEVI u16 f2h(float f) {
  _Float16 h = (_Float16)f;
  return __builtin_bit_cast(u16, h);
}

// async global->LDS, 16 B per lane. LDS dest must be wave-uniform base + lane*16.
DEVI void gload16(const u16* g, u16* l) {
  __builtin_amdgcn_global_load_lds(
      (const __attribute__((address_space(1))) void*)g,
      (__attribute__((address_space(3))) void*)l, 16, 0, 0);
}

// ---- cast x to f16 (for MFMA) and copy x into out[:, :C] (fp32) ----
__global__ void cast_x_copy(const float* __restrict__ x, u16* __restrict__ xh,
                            float* __restrict__ out) {
  size_t i = (size_t)blockIdx.x * blockDim.x + threadIdx.x;  // over B*T*C/4
  float4 v = reinterpret_cast<const float4*>(x)[i];
  ushort4 u;
  u.x = f2h(v.x); u.y = f2h(v.y); u.z = f2h(v.z); u.w = f2h(v.w);
  reinterpret_cast<ushort4*>(xh)[i] = u;
  size_t e = i * 4;
  size_t bt = e / CC;
  int c = (int)(e % CC);
  *reinterpret_cast<float4*>(&out[bt * OUTW + c]) = v;
}

// ---- W [C,N] f32 -> Wt [N,C] f16 ----
__global__ void transpose_cast_w(const float* __restrict__ W, u16* __restrict__ Wt) {
  __shared__ float tile[32][33];
  int n0 = blockIdx.x * 32, c0 = blockIdx.y * 32;
  int tx = threadIdx.x, ty = threadIdx.y;  // 32 x 8
  for (int i = ty; i < 32; i += 8)
    tile[i][tx] = W[(size_t)(c0 + i) * KD + n0 + tx];
  __syncthreads();
  for (int i = ty; i < 32; i += 8)
    Wt[(size_t)(n0 + i) * CC + c0 + tx] = f2h(tile[tx][i]);
}

// ---- V [B,T,VD] f16 -> Vt [B,VD,T] f16 ----
__global__ void transpose_v(const u16* __restrict__ Vn, u16* __restrict__ Vt) {
  __shared__ u16 tile[32][33];
  int b = blockIdx.z;
  int n0 = blockIdx.x * 32, s0 = blockIdx.y * 32;
  const u16* src = Vn + (size_t)b * TT * VD;
  u16* dst = Vt + (size_t)b * VD * TT;
  int tx = threadIdx.x, ty = threadIdx.y;
  for (int i = ty; i < 32; i += 8)
    tile[i][tx] = src[(size_t)(s0 + i) * VD + n0 + tx];
  __syncthreads();
  for (int i = ty; i < 32; i += 8)
    dst[(size_t)(n0 + i) * TT + s0 + tx] = tile[tx][i];
}

// ---- f16 MFMA GEMM (m97 structure): Out = alpha * (A @ Bm^T) (+ bias) ----
// A: [M,Kd] row-major (lda), Bm: [N,Kd] row-major (ldb).
// Linear LDS [128][32] u16 tiles, global_load_lds width-16 staging, 2-barrier loop.
template <typename OutT, bool CSKIP, bool KLIM, bool BIAS>
__global__ __launch_bounds__(256, 2) void gemm_bt(
    const u16* __restrict__ A, const u16* __restrict__ Bm, OutT* __restrict__ Out,
    const float* __restrict__ bias, int Kd, int lda, int ldb, int ldo,
    long long strA, long long strB, long long strO, float alpha) {
  constexpr int BM = 128, BN = 128, BK = 32;
  __shared__ u16 sA[BM * BK];  // 8 KB, linear row-major [128][32]
  __shared__ u16 sB[BN * BK];
  const int r0 = blockIdx.x * BM, c0 = blockIdx.y * BN;
  if (CSKIP && c0 > r0 + BM - 1) return;  // tile entirely masked; never read downstream
  A   += (size_t)blockIdx.z * strA;
  Bm  += (size_t)blockIdx.z * strB;
  Out += (size_t)blockIdx.z * strO;

  const int tid = threadIdx.x;
  const int lane = tid & 63;
  const int w = tid >> 6;

  // staging map: issue i (0/1), wave w, lane l -> LDS byte i*4096 + w*1024 + l*16
  //   -> row = i*64 + w*16 + (l>>2), col = (l&3)*8   (u16 elems)
  const int ld_row = w * 16 + (lane >> 2);
  const int ld_col = (lane & 3) * 8;
  const u16* gA0 = A + (size_t)(r0 + ld_row) * lda + ld_col;
  const u16* gA1 = A + (size_t)(r0 + 64 + ld_row) * lda + ld_col;
  const u16* gB0 = Bm + (size_t)(c0 + ld_row) * ldb + ld_col;
  const u16* gB1 = Bm + (size_t)(c0 + 64 + ld_row) * ldb + ld_col;
  u16* lA0 = sA + (size_t)(w * 64 + lane) * 8;          // byte w*1024 + l*16
  u16* lA1 = sA + 2048 + (size_t)(w * 64 + lane) * 8;   // + 4096 B
  u16* lB0 = sB + (size_t)(w * 64 + lane) * 8;
  u16* lB1 = sB + 2048 + (size_t)(w * 64 + lane) * 8;

  const int wr = (w >> 1) * 64, wc = (w & 1) * 64;  // wave's 64x64 quadrant
  const int l15 = lane & 15, l4 = lane >> 4;

  f32x4 acc[4][4] = {};

  int kmax = Kd;
  if (KLIM) { int km = r0 + BM; kmax = km < Kd ? km : Kd; }

  for (int k0 = 0; k0 < kmax; k0 += BK) {
    __syncthreads();  // previous iteration's LDS frag reads complete
    gload16(gA0 + k0, lA0);
    gload16(gA1 + k0, lA1);
    gload16(gB0 + k0, lB0);
    gload16(gB1 + k0, lB1);
    __syncthreads();  // compiler emits s_waitcnt vmcnt(0) before s_barrier -> LDS valid
    halfx8 af[4], bfr[4];
#pragma unroll
    for (int m = 0; m < 4; ++m)
      af[m] = *reinterpret_cast<const halfx8*>(&sA[(wr + m * 16 + l15) * BK + l4 * 8]);
#pragma unroll
    for (int n = 0; n < 4; ++n)
      bfr[n] = *reinterpret_cast<const halfx8*>(&sB[(wc + n * 16 + l15) * BK + l4 * 8]);
#pragma unroll
    for (int m = 0; m < 4; ++m)
#pragma unroll
      for (int n = 0; n < 4; ++n)
        acc[m][n] = __builtin_amdgcn_mfma_f32_16x16x32_f16(af[m], bfr[n], acc[m][n], 0, 0, 0);
  }

  // epilogue: C/D layout col = lane&15, row = (lane>>4)*4 + reg  [m89/m91 verified]
#pragma unroll
  for (int m = 0; m < 4; ++m) {
    const int growb = r0 + wr + m * 16 + l4 * 4;
#pragma unroll
    for (int n = 0; n < 4; ++n) {
      const int gcol = c0 + wc + n * 16 + l15;
      float bvv = 0.f;
      if (BIAS) bvv = bias[gcol];
#pragma unroll
      for (int r = 0; r < 4; ++r) {
        float val = acc[m][n][r] * alpha + bvv;
        size_t off = (size_t)(growb + r) * ldo + gcol;
        if constexpr (sizeof(OutT) == 2) {
          reinterpret_cast<u16*>(Out)[off] = f2h(val);
        } else {
          reinterpret_cast<float*>(Out)[off] = val;
        }
      }
    }
  }
}

// ---- column softmax over t (axis=1), masked to t >= s ----
// Pass 1: per-(t-chunk) partial (max, sum) per column s. 64-row chunks ->
// 1024 blocks (latency-hiding); max-loop then sum-loop (sum-loop re-reads hit L1/L2,
// exps independent -> pipelined, no serial exp chain).
constexpr int NCH = 32;
constexpr int TCH = TT / NCH;  // 64
__global__ void stats_partial(const float* __restrict__ S, float* __restrict__ Mp,
                              float* __restrict__ Dp) {
  int b = blockIdx.z;
  int s = blockIdx.x * 256 + threadIdx.x;
  int s0 = blockIdx.x * 256;
  int t0 = blockIdx.y * TCH;
  int idx = (blockIdx.y * BB + b) * TT + s;
  float m = -1e30f, d = 0.f;
  if (t0 + TCH - 1 >= s0) {
    const float* Sb = S + (size_t)b * TT * TT;
    if (t0 >= s0 + 255) {  // chunk fully below diagonal for every column in block
      for (int t = t0; t < t0 + TCH; ++t)
        m = fmaxf(m, Sb[(size_t)t * TT + s]);
      for (int t = t0; t < t0 + TCH; ++t)
        d += __expf(Sb[(size_t)t * TT + s] - m);
    } else {
      for (int t = t0; t < t0 + TCH; ++t)
        if (t >= s) m = fmaxf(m, Sb[(size_t)t * TT + s]);
      for (int t = t0; t < t0 + TCH; ++t)
        if (t >= s) d += __expf(Sb[(size_t)t * TT + s] - m);
    }
  }
  Mp[idx] = m;
  Dp[idx] = d;
}

// Pass 2: combine partials -> column max + 1/denominator
__global__ void stats_combine(const float* __restrict__ Mp, const float* __restrict__ Dp,
                              float* __restrict__ Mc, float* __restrict__ Di) {
  int b = blockIdx.y;
  int s = blockIdx.x * 256 + threadIdx.x;
  float m = -1e30f;
  for (int c = 0; c < NCH; ++c) m = fmaxf(m, Mp[(c * BB + b) * TT + s]);
  float d = 0.f;
  for (int c = 0; c < NCH; ++c)
    d += Dp[(c * BB + b) * TT + s] * __expf(Mp[(c * BB + b) * TT + s] - m);
  Mc[b * TT + s] = m;
  Di[b * TT + s] = 1.f / d;  // column always contains the diagonal -> d >= 1
}

// Pass 3: P[t,s] = exp(S[t,s]-M[s])/D[s] for t>=s else 0, stored f16
constexpr int ATCH = 64;
__global__ void softmax_apply(const float* __restrict__ S, const float* __restrict__ Mc,
                              const float* __restrict__ Di, u16* __restrict__ P) {
  int b = blockIdx.z;
  int s = blockIdx.x * 256 + threadIdx.x;
  int s0 = blockIdx.x * 256;
  int t0 = blockIdx.y * ATCH;
  if (s0 > ((t0 + ATCH - 1) | 127)) return;  // outside any PV-read tile band
  const float* Sb = S + (size_t)b * TT * TT;
  u16* Pb = P + (size_t)b * TT * TT;
  float m = Mc[b * TT + s], di = Di[b * TT + s];
  for (int t = t0; t < t0 + ATCH; ++t) {
    float p = 0.f;
    if (t >= s) p = __expf(Sb[(size_t)t * TT + s] - m) * di;
    Pb[(size_t)t * TT + s] = f2h(p);
  }
}

extern "C" void kernel_launch(void* const* d_in, const int* in_sizes, int n_in,
                              void* d_out, int out_size, void* d_ws, size_t ws_size,
                              hipStream_t stream) {
  const float* x  = (const float*)d_in[0];
  const float* Wq = (const float*)d_in[1];
  const float* bq = (const float*)d_in[2];
  const float* Wk = (const float*)d_in[3];
  const float* bk = (const float*)d_in[4];
  const float* Wv = (const float*)d_in[5];
  const float* bv = (const float*)d_in[6];
  float* out = (float*)d_out;
  char* ws = (char*)d_ws;
  constexpr size_t MB = 1024ull * 1024ull;

  // Workspace layout (~135 MB), sequential-reuse aliases:
  u16* xh   = (u16*)(ws);              // 16 MB  [B*T,C] f16
  u16* Qh   = (u16*)(ws + 16 * MB);    // 16 MB
  u16* Kh   = (u16*)(ws + 32 * MB);    // 16 MB
  u16* Vh   = (u16*)(ws + 48 * MB);    // 16 MB (dead after transpose_v)
  u16* Wqt  = (u16*)(ws + 64 * MB);    // 2 MB   [K,C]
  u16* Wkt  = (u16*)(ws + 66 * MB);    // 2 MB
  u16* Wvt  = (u16*)(ws + 68 * MB);    // 2 MB
  float* S  = (float*)(ws + 71 * MB);  // 64 MB  [B,T,T] fp32 logits
  u16* Vt = xh;  // alias: xh dead after V projection; Vt [B,VD,T]
  u16* P  = Qh;  // alias: Qh..Kh (32MB) dead after S GEMM; P [B,T,T] f16
  // stats buffers alias the dead Vh region (stats run after transpose_v):
  float* Mp = (float*)(ws + 48 * MB);               // 1 MB  [NCH,B,T]
  float* Dp = (float*)(ws + 49 * MB);               // 1 MB
  float* Mc = (float*)(ws + 50 * MB);               // 32 KB [B,T]
  float* Di = (float*)(ws + 50 * MB + 64 * 1024);   // 32 KB

  cast_x_copy<<<dim3((BB * TT * CC / 4) / 256), dim3(256), 0, stream>>>(x, xh, out);
  dim3 tb(32, 8);
  transpose_cast_w<<<dim3(KD / 32, CC / 32), tb, 0, stream>>>(Wq, Wqt);
  transpose_cast_w<<<dim3(KD / 32, CC / 32), tb, 0, stream>>>(Wk, Wkt);
  transpose_cast_w<<<dim3(VD / 32, CC / 32), tb, 0, stream>>>(Wv, Wvt);

  // projections: Q/K/V = xh @ Wt^T + b   -> f16 [8192,1024]
  gemm_bt<u16, false, false, true><<<dim3(64, 8, 1), 256, 0, stream>>>(
      xh, Wqt, Qh, bq, CC, CC, CC, KD, 0, 0, 0, 1.f);
  gemm_bt<u16, false, false, true><<<dim3(64, 8, 1), 256, 0, stream>>>(
      xh, Wkt, Kh, bk, CC, CC, CC, KD, 0, 0, 0, 1.f);
  gemm_bt<u16, false, false, true><<<dim3(64, 8, 1), 256, 0, stream>>>(
      xh, Wvt, Vh, bv, CC, CC, CC, VD, 0, 0, 0, 1.f);

  transpose_v<<<dim3(VD / 32, TT / 32, BB), tb, 0, stream>>>(Vh, Vt);

  // S = (Q @ K^T) / sqrt(K), fully-masked tiles skipped
  gemm_bt<float, true, false, false><<<dim3(TT / 128, TT / 128, BB), 256, 0, stream>>>(
      Qh, Kh, S, nullptr, KD, KD, KD, TT,
      (long long)TT * KD, (long long)TT * KD, (long long)TT * TT, INV_SQRT_K);

  // column softmax over t (axis=1)
  stats_partial<<<dim3(TT / 256, NCH, BB), 256, 0, stream>>>(S, Mp, Dp);
  stats_combine<<<dim3(TT / 256, BB), 256, 0, stream>>>(Mp, Dp, Mc, Di);
  softmax_apply<<<dim3(TT / 256, TT / ATCH, BB), 256, 0, stream>>>(S, Mc, Di, P);

  // read = P @ V  (= P @ Vt^T), K truncated at r0+128 (exact: P==0 above diag)
  gemm_bt<float, false, true, false><<<dim3(TT / 128, VD / 128, BB), 256, 0, stream>>>(
      P, Vt, out + CC, nullptr, TT, TT, TT, OUTW,
      (long long)TT * TT, (long long)VD * TT, (long long)TT * OUTW, 1.f);
}

// Round 5
// 269.942 us; speedup vs baseline: 1.2481x; 1.0295x over previous
//
#include <hip/hip_runtime.h>
#include <hip/hip_bf16.h>
#include <stdint.h>

#define DEVI __device__ __forceinline__

using u16 = unsigned short;
typedef __attribute__((ext_vector_type(8))) _Float16 halfx8;
typedef __attribute__((ext_vector_type(4))) float f32x4;

// Problem dims (fixed by the reference)
constexpr int BB = 4, TT = 2048, CC = 1024, KD = 1024, VD = 1024;
constexpr int OUTW = CC + VD;              // 2048
constexpr float INV_SQRT_K = 0.03125f;     // 1/sqrt(1024)

DEVI u16 f2h(float f) {
  _Float16 h = (_Float16)f;
  return __builtin_bit_cast(u16, h);
}

// async global->LDS, 16 B per lane. LDS dest is wave-uniform base + lane*16.
DEVI void gload16(const u16* g, u16* l) {
  __builtin_amdgcn_global_load_lds(
      (const __attribute__((address_space(1))) void*)g,
      (__attribute__((address_space(3))) void*)l, 16, 0, 0);
}

// ---- cast x to f16 (for MFMA) and copy x into out[:, :C] (fp32) ----
__global__ void cast_x_copy(const float* __restrict__ x, u16* __restrict__ xh,
                            float* __restrict__ out) {
  size_t i = (size_t)blockIdx.x * blockDim.x + threadIdx.x;  // over B*T*C/4
  float4 v = reinterpret_cast<const float4*>(x)[i];
  ushort4 u;
  u.x = f2h(v.x); u.y = f2h(v.y); u.z = f2h(v.z); u.w = f2h(v.w);
  reinterpret_cast<ushort4*>(xh)[i] = u;
  size_t e = i * 4;
  size_t bt = e / CC;
  int c = (int)(e % CC);
  *reinterpret_cast<float4*>(&out[bt * OUTW + c]) = v;
}

// ---- W [C,N] f32 -> Wt [N,C] f16 ----
__global__ void transpose_cast_w(const float* __restrict__ W, u16* __restrict__ Wt) {
  __shared__ float tile[32][33];
  int n0 = blockIdx.x * 32, c0 = blockIdx.y * 32;
  int tx = threadIdx.x, ty = threadIdx.y;  // 32 x 8
  for (int i = ty; i < 32; i += 8)
    tile[i][tx] = W[(size_t)(c0 + i) * KD + n0 + tx];
  __syncthreads();
  for (int i = ty; i < 32; i += 8)
    Wt[(size_t)(n0 + i) * CC + c0 + tx] = f2h(tile[tx][i]);
}

// ---- V [B,T,VD] f16 -> Vt [B,VD,T] f16 ----
__global__ void transpose_v(const u16* __restrict__ Vn, u16* __restrict__ Vt) {
  __shared__ u16 tile[32][33];
  int b = blockIdx.z;
  int n0 = blockIdx.x * 32, s0 = blockIdx.y * 32;
  const u16* src = Vn + (size_t)b * TT * VD;
  u16* dst = Vt + (size_t)b * VD * TT;
  int tx = threadIdx.x, ty = threadIdx.y;
  for (int i = ty; i < 32; i += 8)
    tile[i][tx] = src[(size_t)(s0 + i) * VD + n0 + tx];
  __syncthreads();
  for (int i = ty; i < 32; i += 8)
    dst[(size_t)(n0 + i) * TT + s0 + tx] = tile[tx][i];
}

// ---- f16 MFMA GEMM, 2-deep counted-vmcnt pipeline (T3/T4) + XOR swizzle (T2) ----
// A: [M,Kd] row-major (lda), Bm: [N,Kd] row-major (ldb). Out = alpha*(A@Bm^T)(+bias).
// 3 LDS buffers; STAGE(t+2) issued before MFMA(t); vmcnt(4) (never 0 in steady
// state) + raw s_barrier once per K-step; lgkmcnt(0) before the barrier so
// pending ds_reads can't race the next buffer overwrite.
// Swizzle (both-sides, rule 21): LDS dest linear; global source col pre-swizzled
// with involution col8 ^= (row>>1)&3; frag read applies the same involution.
template <typename OutT, bool CSKIP, bool KLIM, bool BIAS>
__global__ __launch_bounds__(256, 2) void gemm_bt(
    const u16* __restrict__ A, const u16* __restrict__ Bm, OutT* __restrict__ Out,
    const float* __restrict__ bias, int Kd, int lda, int ldb, int ldo,
    long long strA, long long strB, long long strO, float alpha) {
  constexpr int BM = 128, BN = 128, BK = 32;
  __shared__ u16 sA[3 * BM * BK];  // 3 x 8 KB
  __shared__ u16 sB[3 * BN * BK];
  const int r0 = blockIdx.x * BM, c0 = blockIdx.y * BN;
  if (CSKIP && c0 > r0 + BM - 1) return;  // tile entirely masked; never read downstream
  A   += (size_t)blockIdx.z * strA;
  Bm  += (size_t)blockIdx.z * strB;
  Out += (size_t)blockIdx.z * strO;

  const int tid = threadIdx.x;
  const int lane = tid & 63;
  const int w = tid >> 6;

  // staging: issue i covers row = i*64 + w*16 + (lane>>2); source col swizzled.
  const int srow = w * 16 + (lane >> 2);
  const int scol = 8 * ((lane & 3) ^ ((lane >> 3) & 3));  // == 8*((lane&3)^((srow>>1)&3))
  const u16* gA0 = A + (size_t)(r0 + srow) * lda + scol;
  const u16* gA1 = A + (size_t)(r0 + 64 + srow) * lda + scol;
  const u16* gB0 = Bm + (size_t)(c0 + srow) * ldb + scol;
  const u16* gB1 = Bm + (size_t)(c0 + 64 + srow) * ldb + scol;
  const int ldst = w * 512 + lane * 8;  // u16 offset inside a buffer (linear dest)

  const int wr = (w >> 1) * 64, wc = (w & 1) * 64;  // wave's 64x64 quadrant
  const int l15 = lane & 15, l4 = lane >> 4;
  const int csw = 8 * (l4 ^ ((l15 >> 1) & 3));  // swizzled read col (u16 elems)

  f32x4 acc[4][4] = {};

  int kmax = Kd;
  if (KLIM) { int km = r0 + BM; kmax = km < Kd ? km : Kd; }
  const int nt = kmax / BK;  // >= 4 for all call sites

  auto STAGE = [&](int buf, int t) {
    const int k0 = t * BK;
    u16* la = sA + buf * 4096 + ldst;
    u16* lb = sB + buf * 4096 + ldst;
    gload16(gA0 + k0, la);
    gload16(gA1 + k0, la + 2048);
    gload16(gB0 + k0, lb);
    gload16(gB1 + k0, lb + 2048);
  };

  STAGE(0, 0);
  STAGE(1, 1);
  asm volatile("s_waitcnt vmcnt(4)" ::: "memory");  // buf0's 4 loads complete (in-order)
  __builtin_amdgcn_s_barrier();

  for (int t = 0; t < nt; ++t) {
    const int buf = t - (t / 3) * 3;  // t % 3
    const u16* bA = sA + buf * 4096;
    const u16* bB = sB + buf * 4096;
    halfx8 af[4], bfr[4];
#pragma unroll
    for (int m = 0; m < 4; ++m)
      af[m] = *reinterpret_cast<const halfx8*>(&bA[(wr + m * 16 + l15) * BK + csw]);
#pragma unroll
    for (int n = 0; n < 4; ++n)
      bfr[n] = *reinterpret_cast<const halfx8*>(&bB[(wc + n * 16 + l15) * BK + csw]);
    if (t + 2 < nt) {
      int nb = buf + 2;
      if (nb >= 3) nb -= 3;      // (t+2) % 3 — NOT the buffer being read now
      STAGE(nb, t + 2);
    }
    asm volatile("s_waitcnt lgkmcnt(0)" ::: "memory");  // frags in regs before barrier
    __builtin_amdgcn_s_setprio(1);
#pragma unroll
    for (int m = 0; m < 4; ++m)
#pragma unroll
      for (int n = 0; n < 4; ++n)
        acc[m][n] = __builtin_amdgcn_mfma_f32_16x16x32_f16(af[m], bfr[n], acc[m][n], 0, 0, 0);
    __builtin_amdgcn_s_setprio(0);
    if (t + 1 < nt) {
      if (t + 2 < nt) asm volatile("s_waitcnt vmcnt(4)" ::: "memory");  // t+1 ready, t+2 in flight
      else            asm volatile("s_waitcnt vmcnt(0)" ::: "memory");  // drain tail
      __builtin_amdgcn_s_barrier();
    }
  }

  // epilogue: C/D layout col = lane&15, row = (lane>>4)*4 + reg  [m89/m91 verified]
#pragma unroll
  for (int m = 0; m < 4; ++m) {
    const int growb = r0 + wr + m * 16 + l4 * 4;
#pragma unroll
    for (int n = 0; n < 4; ++n) {
      const int gcol = c0 + wc + n * 16 + l15;
      float bvv = 0.f;
      if (BIAS) bvv = bias[gcol];
#pragma unroll
      for (int r = 0; r < 4; ++r) {
        float val = acc[m][n][r] * alpha + bvv;
        size_t off = (size_t)(growb + r) * ldo + gcol;
        if constexpr (sizeof(OutT) == 2) {
          reinterpret_cast<u16*>(Out)[off] = f2h(val);
        } else {
          reinterpret_cast<float*>(Out)[off] = val;
        }
      }
    }
  }
}

// ---- column softmax over t (axis=1), masked to t >= s ----
constexpr int NCH = 32;
constexpr int TCH = TT / NCH;  // 64
__global__ void stats_partial(const float* __restrict__ S, float* __restrict__ Mp,
                              float* __restrict__ Dp) {
  int b = blockIdx.z;
  int s = blockIdx.x * 256 + threadIdx.x;
  int s0 = blockIdx.x * 256;
  int t0 = blockIdx.y * TCH;
  int idx = (blockIdx.y * BB + b) * TT + s;
  float m = -1e30f, d = 0.f;
  if (t0 + TCH - 1 >= s0) {
    const float* Sb = S + (size_t)b * TT * TT;
    if (t0 >= s0 + 255) {  // chunk fully below diagonal for every column in block
      for (int t = t0; t < t0 + TCH; ++t)
        m = fmaxf(m, Sb[(size_t)t * TT + s]);
      for (int t = t0; t < t0 + TCH; ++t)
        d += __expf(Sb[(size_t)t * TT + s] - m);
    } else {
      for (int t = t0; t < t0 + TCH; ++t)
        if (t >= s) m = fmaxf(m, Sb[(size_t)t * TT + s]);
      for (int t = t0; t < t0 + TCH; ++t)
        if (t >= s) d += __expf(Sb[(size_t)t * TT + s] - m);
    }
  }
  Mp[idx] = m;
  Dp[idx] = d;
}

__global__ void stats_combine(const float* __restrict__ Mp, const float* __restrict__ Dp,
                              float* __restrict__ Mc, float* __restrict__ Di) {
  int b = blockIdx.y;
  int s = blockIdx.x * 256 + threadIdx.x;
  float m = -1e30f;
  for (int c = 0; c < NCH; ++c) m = fmaxf(m, Mp[(c * BB + b) * TT + s]);
  float d = 0.f;
  for (int c = 0; c < NCH; ++c)
    d += Dp[(c * BB + b) * TT + s] * __expf(Mp[(c * BB + b) * TT + s] - m);
  Mc[b * TT + s] = m;
  Di[b * TT + s] = 1.f / d;  // column always contains the diagonal -> d >= 1
}

constexpr int ATCH = 64;
__global__ void softmax_apply(const float* __restrict__ S, const float* __restrict__ Mc,
                              const float* __restrict__ Di, u16* __restrict__ P) {
  int b = blockIdx.z;
  int s = blockIdx.x * 256 + threadIdx.x;
  int s0 = blockIdx.x * 256;
  int t0 = blockIdx.y * ATCH;
  if (s0 > ((t0 + ATCH - 1) | 127)) return;  // outside any PV-read tile band
  const float* Sb = S + (size_t)b * TT * TT;
  u16* Pb = P + (size_t)b * TT * TT;
  float m = Mc[b * TT + s], di = Di[b * TT + s];
  for (int t = t0; t < t0 + ATCH; ++t) {
    float p = 0.f;
    if (t >= s) p = __expf(Sb[(size_t)t * TT + s] - m) * di;
    Pb[(size_t)t * TT + s] = f2h(p);
  }
}

extern "C" void kernel_launch(void* const* d_in, const int* in_sizes, int n_in,
                              void* d_out, int out_size, void* d_ws, size_t ws_size,
                              hipStream_t stream) {
  const float* x  = (const float*)d_in[0];
  const float* Wq = (const float*)d_in[1];
  const float* bq = (const float*)d_in[2];
  const float* Wk = (const float*)d_in[3];
  const float* bk = (const float*)d_in[4];
  const float* Wv = (const float*)d_in[5];
  const float* bv = (const float*)d_in[6];
  float* out = (float*)d_out;
  char* ws = (char*)d_ws;
  constexpr size_t MB = 1024ull * 1024ull;

  u16* xh   = (u16*)(ws);              // 16 MB  [B*T,C] f16
  u16* Qh   = (u16*)(ws + 16 * MB);    // 16 MB
  u16* Kh   = (u16*)(ws + 32 * MB);    // 16 MB
  u16* Vh   = (u16*)(ws + 48 * MB);    // 16 MB (dead after transpose_v)
  u16* Wqt  = (u16*)(ws + 64 * MB);    // 2 MB   [K,C]
  u16* Wkt  = (u16*)(ws + 66 * MB);    // 2 MB
  u16* Wvt  = (u16*)(ws + 68 * MB);    // 2 MB
  float* S  = (float*)(ws + 71 * MB);  // 64 MB  [B,T,T] fp32 logits
  u16* Vt = xh;  // alias: xh dead after V projection; Vt [B,VD,T]
  u16* P  = Qh;  // alias: Qh..Kh (32MB) dead after S GEMM; P [B,T,T] f16
  float* Mp = (float*)(ws + 48 * MB);               // 1 MB  [NCH,B,T]
  float* Dp = (float*)(ws + 49 * MB);               // 1 MB
  float* Mc = (float*)(ws + 50 * MB);               // 32 KB [B,T]
  float* Di = (float*)(ws + 50 * MB + 64 * 1024);   // 32 KB

  cast_x_copy<<<dim3((BB * TT * CC / 4) / 256), dim3(256), 0, stream>>>(x, xh, out);
  dim3 tb(32, 8);
  transpose_cast_w<<<dim3(KD / 32, CC / 32), tb, 0, stream>>>(Wq, Wqt);
  transpose_cast_w<<<dim3(KD / 32, CC / 32), tb, 0, stream>>>(Wk, Wkt);
  transpose_cast_w<<<dim3(VD / 32, CC / 32), tb, 0, stream>>>(Wv, Wvt);

  gemm_bt<u16, false, false, true><<<dim3(64, 8, 1), 256, 0, stream>>>(
      xh, Wqt, Qh, bq, CC, CC, CC, KD, 0, 0, 0, 1.f);
  gemm_bt<u16, false, false, true><<<dim3(64, 8, 1), 256, 0, stream>>>(
      xh, Wkt, Kh, bk, CC, CC, CC, KD, 0, 0, 0, 1.f);
  gemm_bt<u16, false, false, true><<<dim3(64, 8, 1), 256, 0, stream>>>(
      xh, Wvt, Vh, bv, CC, CC, CC, VD, 0, 0, 0, 1.f);

  transpose_v<<<dim3(VD / 32, TT / 32, BB), tb, 0, stream>>>(Vh, Vt);

  gemm_bt<float, true, false, false><<<dim3(TT / 128, TT / 128, BB), 256, 0, stream>>>(
      Qh, Kh, S, nullptr, KD, KD, KD, TT,
      (long long)TT * KD, (long long)TT * KD, (long long)TT * TT, INV_SQRT_K);

  stats_partial<<<dim3(TT / 256, NCH, BB), 256, 0, stream>>>(S, Mp, Dp);
  stats_combine<<<dim3(TT / 256, BB), 256, 0, stream>>>(Mp, Dp, Mc, Di);
  softmax_apply<<<dim3(TT / 256, TT / ATCH, BB), 256, 0, stream>>>(S, Mc, Di, P);

  gemm_bt<float, false, true, false><<<dim3(TT / 128, VD / 128, BB), 256, 0, stream>>>(
      P, Vt, out + CC, nullptr, TT, TT, TT, OUTW,
      (long long)TT * TT, (long long)VD * TT, (long long)TT * OUTW, 1.f);
}